// Round 2
// baseline (1233.614 us; speedup 1.0000x reference)
//
#include <hip/hip_runtime.h>
#include <stdint.h>

// Fused 2-layer LSTM: B=2048, T=512, F=32, H=128, G=512. One WG (512 thr,
// 8 waves) per 8 batch rows; 256 WGs = 1/CU. Single 513-iteration loop:
// iteration tau runs layer-0 step tau AND layer-1 step tau-1 (skewed).
// Weights mostly register-resident: Wih0 (16 regs), Whh0 (64), Whh1 (64),
// Wih1 kc=0,1 (32) in VGPR/AGPR. Streamed per-iter from a 64 KB
// phase-contiguous LDS image: Wih1 kc=2,3 (8 ds_read_b128/lane). Cuts per-CU
// LDS traffic/iter ~195 KB -> ~128 KB; the old 133 KB bank-padded image is
// gone (LDS 142.8 KB -> 75 KB). Layer-0 gates are evaluated before the
// layer-1 MFMAs so acc0 dies early, and the streamed kc=3 set (w1s1) is
// loaded only AFTER the kc=2 set (w1s0) is consumed, so the two never
// overlap -> peak live regs ~242 of the 256 budget at 2 waves/SIMD.
// h passes through LDS only; FC tail reads h1(T-1) back from LDS.

#define B_ 2048
#define T_ 512
#define F_ 32
#define H_ 128
#define LSTR 144                 // halves per h-buffer row
#define H0SZ (8 * LSTR)          // halves per h buffer
#define W1STR 4096               // halves per wave in streamed-Wih1 LDS image

#define LOG2E 1.4426950408889634f

typedef _Float16 half8 __attribute__((ext_vector_type(8)));
typedef float float4_t __attribute__((ext_vector_type(4)));

// lgkm-only barrier: don't drain vmcnt (global x prefetch stays in flight).
// The "memory" clobber also stops the compiler from hoisting the
// loop-invariant streamed-weight ds_reads out of the loop (which would
// re-balloon register pressure).
#define BARRIER_LGKM() asm volatile("s_waitcnt lgkmcnt(0)\n\ts_barrier" ::: "memory")

__device__ __forceinline__ float fexp2(float x) {
  float r; asm("v_exp_f32 %0, %1" : "=v"(r) : "v"(x)); return r;
}
__device__ __forceinline__ float frcp(float x) { return __builtin_amdgcn_rcpf(x); }

__device__ __forceinline__ half8 cvt2f4(float4_t a, float4_t b) {
  half8 r;
  r[0] = (_Float16)a[0]; r[1] = (_Float16)a[1]; r[2] = (_Float16)a[2]; r[3] = (_Float16)a[3];
  r[4] = (_Float16)b[0]; r[5] = (_Float16)b[1]; r[6] = (_Float16)b[2]; r[7] = (_Float16)b[3];
  return r;
}
__device__ __forceinline__ half8 load8cvt(const float* p) {
  return cvt2f4(*(const float4_t*)p, *(const float4_t*)(p + 4));
}

__global__ __launch_bounds__(512, 2) void lstm_fused(
    const float* __restrict__ x, const float* __restrict__ Wih0,
    const float* __restrict__ Whh0, const float* __restrict__ b0,
    const float* __restrict__ Wih1, const float* __restrict__ Whh1,
    const float* __restrict__ b1, const float* __restrict__ Wfc,
    const float* __restrict__ bfc, float* __restrict__ out)
{
  __shared__ __attribute__((aligned(16))) _Float16 lds_w1[8 * W1STR];  // 65536 B
  __shared__ __attribute__((aligned(16))) _Float16 lds_h0[2 * H0SZ];   // 4608 B
  __shared__ __attribute__((aligned(16))) _Float16 lds_h1[2 * H0SZ];   // 4608 B
  __shared__ float lds_fc[8][8];

  const int tid  = threadIdx.x;
  const int w    = tid >> 6;
  const int lane = tid & 63;
  const int n    = lane & 15;
  const int q    = lane >> 4;
  const int rbase = (int)blockIdx.x * 8;
  const int rload = rbase + (n & 7);
  const int rsh  = (q >> 1) * 2;            // acc regs this lane finalizes
  const int rowq = (q & 1) * 4;             // base output row
  const int colg = w * 16 + n;              // this lane's h-column
  const int aoff = (n & 7) * LSTR + q * 8;  // A-frag read offset (halves)

  // ---- setup: weights -> regs; Wih1 kc=2,3 -> phase-contiguous LDS ----
  // Streamed image layout: per wave block of 4096 halves; frag slot
  // (j*2+kc') stride 512 halves; within a frag, lane (q,n) owns halves
  // q*128 + n*8  ->  the wave's 64 lanes read 1024 contiguous bytes per
  // slot: conflict-free ds_read_b128.
  half8 bwih0[4], bwhh0[4][4], bwhh1[4][4], bwih1r[2][4];
  _Float16* w1base = lds_w1 + w * W1STR + q * 128 + n * 8;
#pragma unroll
  for (int j = 0; j < 4; ++j) {
    const int g = j * H_ + colg;            // == (j*8+w)*16+n
    bwih0[j] = load8cvt(Wih0 + g * F_ + q * 8);
#pragma unroll
    for (int kc = 0; kc < 4; ++kc) {
      bwhh0[j][kc] = load8cvt(Whh0 + g * H_ + kc * 32 + q * 8);
      bwhh1[j][kc] = load8cvt(Whh1 + g * H_ + kc * 32 + q * 8);
    }
    bwih1r[0][j] = load8cvt(Wih1 + g * H_ + 0 * 32 + q * 8);
    bwih1r[1][j] = load8cvt(Wih1 + g * H_ + 1 * 32 + q * 8);
    *(half8*)(w1base + (j * 2 + 0) * 512) = load8cvt(Wih1 + g * H_ + 2 * 32 + q * 8);
    *(half8*)(w1base + (j * 2 + 1) * 512) = load8cvt(Wih1 + g * H_ + 3 * 32 + q * 8);
  }
  // folded gate biases (log2 domain), packed f16 to save 4 VGPRs:
  // [cI0,cF0,cG0,cO0,cI1,cF1,cG1,cO1]
  half8 cpack;
  cpack[0] = (_Float16)(-b0[0 * H_ + colg] * LOG2E);
  cpack[1] = (_Float16)(-b0[1 * H_ + colg] * LOG2E);
  cpack[2] = (_Float16)( b0[2 * H_ + colg] * (2.0f * LOG2E));
  cpack[3] = (_Float16)(-b0[3 * H_ + colg] * LOG2E);
  cpack[4] = (_Float16)(-b1[0 * H_ + colg] * LOG2E);
  cpack[5] = (_Float16)(-b1[1 * H_ + colg] * LOG2E);
  cpack[6] = (_Float16)( b1[2 * H_ + colg] * (2.0f * LOG2E));
  cpack[7] = (_Float16)(-b1[3 * H_ + colg] * LOG2E);

  for (int i = tid; i < 2 * H0SZ; i += 512) { lds_h0[i] = (_Float16)0.0f; lds_h1[i] = (_Float16)0.0f; }
  __syncthreads();

  const float4_t zC = {0.f, 0.f, 0.f, 0.f};
  float c00 = 0.f, c01 = 0.f;      // layer-0 cell state (2 rows)
  float c10 = 0.f, c11 = 0.f;      // layer-1 cell state

  const float* xptr = x + rload * (T_ * F_) + q * 8;
  float4_t xrA = *(const float4_t*)(xptr);
  float4_t xrB = *(const float4_t*)(xptr + 4);

#pragma unroll 1
  for (int tau = 0; tau <= T_; ++tau) {
    const int pw = tau & 1;
    _Float16* h0rd = lds_h0 + (pw ^ 1) * H0SZ;   // h0(tau-1)
    _Float16* h0wr = lds_h0 + pw * H0SZ;         // h0(tau)
    _Float16* h1rd = lds_h1 + pw * H0SZ;         // h1(tau-2)
    _Float16* h1wr = lds_h1 + (pw ^ 1) * H0SZ;   // h1(tau-1)
    const bool do0 = (tau < T_), do1 = (tau >= 1);

    half8 ah[4];                                  // h0(tau-1): shared A-frag
#pragma unroll
    for (int kc = 0; kc < 4; ++kc)
      ah[kc] = *(const half8*)(h0rd + aoff + kc * 32);
    half8 w1s0[4];                                // Wih1 kc=2 frags (streamed)
#pragma unroll
    for (int j = 0; j < 4; ++j)
      w1s0[j] = *(const half8*)(w1base + (j * 2 + 0) * 512);

    float4_t acc0[4];
    if (do0) {                                    // layer 0, step tau
      half8 ax = cvt2f4(xrA, xrB);
#pragma unroll
      for (int j = 0; j < 4; ++j)
        acc0[j] = __builtin_amdgcn_mfma_f32_16x16x32_f16(ax, bwih0[j], zC, 0, 0, 0);
#pragma unroll
      for (int kc = 0; kc < 4; ++kc)
#pragma unroll
        for (int j = 0; j < 4; ++j)
          acc0[j] = __builtin_amdgcn_mfma_f32_16x16x32_f16(ah[kc], bwhh0[j][kc], acc0[j], 0, 0, 0);
      const int tn = (tau + 1 < T_) ? tau + 1 : T_ - 1;   // x prefetch (f32,
      xrA = *(const float4_t*)(xptr + tn * F_);           //  cvt at use so the
      xrB = *(const float4_t*)(xptr + tn * F_ + 4);       //  load spans iters)
    }
    if (do0) {                                    // layer-0 gates (acc0 dies)
#pragma unroll
      for (int rr = 0; rr < 2; ++rr) {
        const int ri = rsh + rr;
        const float gi = frcp(1.0f + fexp2(__builtin_fmaf(acc0[0][ri], -LOG2E, (float)cpack[0])));
        const float gf = frcp(1.0f + fexp2(__builtin_fmaf(acc0[1][ri], -LOG2E, (float)cpack[1])));
        const float gg = 1.0f - 2.0f * frcp(1.0f + fexp2(__builtin_fmaf(acc0[2][ri], 2.0f * LOG2E, (float)cpack[2])));
        const float go = frcp(1.0f + fexp2(__builtin_fmaf(acc0[3][ri], -LOG2E, (float)cpack[3])));
        float& cc = rr ? c01 : c00;
        cc = __builtin_fmaf(gf, cc, gi * gg);
        const float th = 1.0f - 2.0f * frcp(1.0f + fexp2(cc * (2.0f * LOG2E)));
        h0wr[(rowq + ri) * LSTR + colg] = (_Float16)(go * th);
      }
    }
    if (do1) {                                    // layer 1, step tau-1
      float4_t acc1[4];
#pragma unroll
      for (int j = 0; j < 4; ++j)                 // ih: cached kc=0
        acc1[j] = __builtin_amdgcn_mfma_f32_16x16x32_f16(ah[0], bwih1r[0][j], zC, 0, 0, 0);
#pragma unroll
      for (int j = 0; j < 4; ++j)                 // ih: cached kc=1
        acc1[j] = __builtin_amdgcn_mfma_f32_16x16x32_f16(ah[1], bwih1r[1][j], acc1[j], 0, 0, 0);
#pragma unroll
      for (int j = 0; j < 4; ++j)                 // ih: streamed kc=2 (w1s0 dies)
        acc1[j] = __builtin_amdgcn_mfma_f32_16x16x32_f16(ah[2], w1s0[j], acc1[j], 0, 0, 0);
      half8 w1s1[4];                              // Wih1 kc=3 frags (streamed;
#pragma unroll                                    //  issued only after w1s0 use
      for (int j = 0; j < 4; ++j)                 //  -> no live overlap)
        w1s1[j] = *(const half8*)(w1base + (j * 2 + 1) * 512);
      half8 a1h[4];                               // h1(tau-2)
#pragma unroll
      for (int kc = 0; kc < 4; ++kc)
        a1h[kc] = *(const half8*)(h1rd + aoff + kc * 32);
#pragma unroll
      for (int j = 0; j < 4; ++j)                 // ih: streamed kc=3
        acc1[j] = __builtin_amdgcn_mfma_f32_16x16x32_f16(ah[3], w1s1[j], acc1[j], 0, 0, 0);
#pragma unroll
      for (int kc = 0; kc < 4; ++kc)              // hh
#pragma unroll
        for (int j = 0; j < 4; ++j)
          acc1[j] = __builtin_amdgcn_mfma_f32_16x16x32_f16(a1h[kc], bwhh1[j][kc], acc1[j], 0, 0, 0);
#pragma unroll
      for (int rr = 0; rr < 2; ++rr) {            // layer-1 gates
        const int ri = rsh + rr;
        const float gi = frcp(1.0f + fexp2(__builtin_fmaf(acc1[0][ri], -LOG2E, (float)cpack[4])));
        const float gf = frcp(1.0f + fexp2(__builtin_fmaf(acc1[1][ri], -LOG2E, (float)cpack[5])));
        const float gg = 1.0f - 2.0f * frcp(1.0f + fexp2(__builtin_fmaf(acc1[2][ri], 2.0f * LOG2E, (float)cpack[6])));
        const float go = frcp(1.0f + fexp2(__builtin_fmaf(acc1[3][ri], -LOG2E, (float)cpack[7])));
        float& cc = rr ? c11 : c10;
        cc = __builtin_fmaf(gf, cc, gi * gg);
        const float th = 1.0f - 2.0f * frcp(1.0f + fexp2(cc * (2.0f * LOG2E)));
        h1wr[(rowq + ri) * LSTR + colg] = (_Float16)(go * th);
      }
    }
    BARRIER_LGKM();
  }

  // ---- FC head: out[row] = sum_c h1_last[row][c]*Wfc[c] + bfc ----
  // h1(T-1) sits in lds_h1 + H0SZ (tau=T_ wrote it there); read back the
  // two values this lane produced instead of carrying them in registers.
  const float wfcv = Wfc[colg];
  float p0 = (float)lds_h1[H0SZ + (rowq + rsh + 0) * LSTR + colg] * wfcv;
  float p1 = (float)lds_h1[H0SZ + (rowq + rsh + 1) * LSTR + colg] * wfcv;
#pragma unroll
  for (int m = 1; m < 16; m <<= 1) {
    p0 += __shfl_xor(p0, m);
    p1 += __shfl_xor(p1, m);
  }
  if (n == 0) {
    lds_fc[w][rowq + rsh + 0] = p0;
    lds_fc[w][rowq + rsh + 1] = p1;
  }
  __syncthreads();
  if (tid < 8) {
    float s = bfc[0];
#pragma unroll
    for (int wv = 0; wv < 8; ++wv) s += lds_fc[wv][tid];
    out[rbase + tid] = s;
  }
}

extern "C" void kernel_launch(void* const* d_in, const int* in_sizes, int n_in,
                              void* d_out, int out_size, void* d_ws, size_t ws_size,
                              hipStream_t stream) {
  const float* x    = (const float*)d_in[0];
  const float* Wih0 = (const float*)d_in[1];
  const float* Whh0 = (const float*)d_in[2];
  const float* b0   = (const float*)d_in[3];
  const float* Wih1 = (const float*)d_in[4];
  const float* Whh1 = (const float*)d_in[5];
  const float* b1   = (const float*)d_in[6];
  const float* Wfc  = (const float*)d_in[7];
  const float* bfc  = (const float*)d_in[8];
  float* outp = (float*)d_out;
  (void)d_ws; (void)ws_size;

  lstm_fused<<<B_ / 8, 512, 0, stream>>>(x, Wih0, Whh0, b0, Wih1, Whh1, b1,
                                         Wfc, bfc, outp);
}

// Round 3
// 980.365 us; speedup vs baseline: 1.2583x; 1.2583x over previous
//
#include <hip/hip_runtime.h>
#include <stdint.h>

// Fused 2-layer LSTM: B=2048, T=512, F=32, H=128, G=512. One WG (512 thr,
// 8 waves) per 8 batch rows; 256 WGs = 1/CU. Single 513-iteration loop:
// iteration tau runs layer-0 step tau AND layer-1 step tau-1 (skewed).
// ROUND 3 = round-0 register budget + round-2 conflict-free LDS image:
//  - Register-resident weights: Wih0 (16) + Whh0 (64) + Whh1 (64) = 144 regs
//    (compiler places them in AGPR; MFMA reads A/B from AGPR on gfx950).
//    Wih1 is NOT register-cached (round 2 proved that spills: +46 MB scratch
//    writes/iter aggregate, dur 1054->1233).
//  - Wih1 streamed per-iter from a slot-contiguous LDS image: 16 slots/wave
//    (kc*4+j), 1024 B each, lane offset q*128+n*8 halves -> each
//    ds_read_b128 reads 1024 contiguous bytes per wave: conflict-free
//    (round 2 measured 7.55e7 -> 8.4e6 bank-conflict cycles with this).
//  - Streamed kc-phases are double-buffered (w1a/w1b, 32 regs max) so the
//    lgkm wait of phase kc+1 hides under the 4 MFMAs of phase kc.
//  - Layer-0 gates evaluated before layer-1 MFMAs so acc0 dies early.
// Peak live ~= 144 AGPR + ~110 VGPR < 256 total at 2 waves/SIMD: no spill.
// h passes through LDS only; FC tail reads h1(T-1) back from LDS.

#define B_ 2048
#define T_ 512
#define F_ 32
#define H_ 128
#define LSTR 144                 // halves per h-buffer row
#define H0SZ (8 * LSTR)          // halves per h buffer
#define W1STR 8192               // halves per wave in streamed-Wih1 LDS image

#define LOG2E 1.4426950408889634f

typedef _Float16 half8 __attribute__((ext_vector_type(8)));
typedef float float4_t __attribute__((ext_vector_type(4)));

// lgkm-only barrier: don't drain vmcnt (global x prefetch stays in flight).
// The "memory" clobber also stops the compiler from hoisting the
// loop-invariant streamed-weight ds_reads out of the loop (which would
// re-balloon register pressure).
#define BARRIER_LGKM() asm volatile("s_waitcnt lgkmcnt(0)\n\ts_barrier" ::: "memory")

__device__ __forceinline__ float fexp2(float x) {
  float r; asm("v_exp_f32 %0, %1" : "=v"(r) : "v"(x)); return r;
}
__device__ __forceinline__ float frcp(float x) { return __builtin_amdgcn_rcpf(x); }

__device__ __forceinline__ half8 cvt2f4(float4_t a, float4_t b) {
  half8 r;
  r[0] = (_Float16)a[0]; r[1] = (_Float16)a[1]; r[2] = (_Float16)a[2]; r[3] = (_Float16)a[3];
  r[4] = (_Float16)b[0]; r[5] = (_Float16)b[1]; r[6] = (_Float16)b[2]; r[7] = (_Float16)b[3];
  return r;
}
__device__ __forceinline__ half8 load8cvt(const float* p) {
  return cvt2f4(*(const float4_t*)p, *(const float4_t*)(p + 4));
}

__global__ __launch_bounds__(512, 2) void lstm_fused(
    const float* __restrict__ x, const float* __restrict__ Wih0,
    const float* __restrict__ Whh0, const float* __restrict__ b0,
    const float* __restrict__ Wih1, const float* __restrict__ Whh1,
    const float* __restrict__ b1, const float* __restrict__ Wfc,
    const float* __restrict__ bfc, float* __restrict__ out)
{
  __shared__ __attribute__((aligned(16))) _Float16 lds_w1[8 * W1STR];  // 131072 B
  __shared__ __attribute__((aligned(16))) _Float16 lds_h0[2 * H0SZ];   // 4608 B
  __shared__ __attribute__((aligned(16))) _Float16 lds_h1[2 * H0SZ];   // 4608 B
  __shared__ float lds_fc[8][8];

  const int tid  = threadIdx.x;
  const int w    = tid >> 6;
  const int lane = tid & 63;
  const int n    = lane & 15;
  const int q    = lane >> 4;
  const int rbase = (int)blockIdx.x * 8;
  const int rload = rbase + (n & 7);
  const int rsh  = (q >> 1) * 2;            // acc regs this lane finalizes
  const int rowq = (q & 1) * 4;             // base output row
  const int colg = w * 16 + n;              // this lane's h-column
  const int aoff = (n & 7) * LSTR + q * 8;  // A-frag read offset (halves)

  // ---- setup: Wih0/Whh0/Whh1 -> regs; Wih1 -> slot-contiguous LDS ----
  // Image layout: per wave block of 8192 halves; slot (kc*4+j) stride 512
  // halves; within a slot, lane (q,n) owns halves q*128 + n*8 -> the wave's
  // 64 lanes read 1024 contiguous bytes per slot: conflict-free ds_read_b128.
  half8 bwih0[4], bwhh0[4][4], bwhh1[4][4];
  _Float16* w1base = lds_w1 + w * W1STR + q * 128 + n * 8;
#pragma unroll
  for (int j = 0; j < 4; ++j) {
    const int g = j * H_ + colg;            // == (j*8+w)*16+n
    bwih0[j] = load8cvt(Wih0 + g * F_ + q * 8);
#pragma unroll
    for (int kc = 0; kc < 4; ++kc) {
      bwhh0[j][kc] = load8cvt(Whh0 + g * H_ + kc * 32 + q * 8);
      bwhh1[j][kc] = load8cvt(Whh1 + g * H_ + kc * 32 + q * 8);
      *(half8*)(w1base + (kc * 4 + j) * 512) = load8cvt(Wih1 + g * H_ + kc * 32 + q * 8);
    }
  }
  // folded gate biases (log2 domain): sig(z+b)=rcp(1+2^(-z*log2e - b*log2e)),
  // tanh(z+b)=1-2*rcp(1+2^(2z*log2e + 2b*log2e))
  const float cI0 = -b0[0 * H_ + colg] * LOG2E;
  const float cF0 = -b0[1 * H_ + colg] * LOG2E;
  const float cG0 =  b0[2 * H_ + colg] * (2.0f * LOG2E);
  const float cO0 = -b0[3 * H_ + colg] * LOG2E;
  const float cI1 = -b1[0 * H_ + colg] * LOG2E;
  const float cF1 = -b1[1 * H_ + colg] * LOG2E;
  const float cG1 =  b1[2 * H_ + colg] * (2.0f * LOG2E);
  const float cO1 = -b1[3 * H_ + colg] * LOG2E;

  for (int i = tid; i < 2 * H0SZ; i += 512) { lds_h0[i] = (_Float16)0.0f; lds_h1[i] = (_Float16)0.0f; }
  __syncthreads();

  const float4_t zC = {0.f, 0.f, 0.f, 0.f};
  float c00 = 0.f, c01 = 0.f;      // layer-0 cell state (2 rows)
  float c10 = 0.f, c11 = 0.f;      // layer-1 cell state

  const float* xptr = x + rload * (T_ * F_) + q * 8;
  float4_t xrA = *(const float4_t*)(xptr);
  float4_t xrB = *(const float4_t*)(xptr + 4);

#pragma unroll 1
  for (int tau = 0; tau <= T_; ++tau) {
    const int pw = tau & 1;
    _Float16* h0rd = lds_h0 + (pw ^ 1) * H0SZ;   // h0(tau-1)
    _Float16* h0wr = lds_h0 + pw * H0SZ;         // h0(tau)
    _Float16* h1rd = lds_h1 + pw * H0SZ;         // h1(tau-2)
    _Float16* h1wr = lds_h1 + (pw ^ 1) * H0SZ;   // h1(tau-1)
    const bool do0 = (tau < T_), do1 = (tau >= 1);

    half8 ah[4];                                  // h0(tau-1): shared A-frag
#pragma unroll
    for (int kc = 0; kc < 4; ++kc)
      ah[kc] = *(const half8*)(h0rd + aoff + kc * 32);
    half8 w1a[4];                                 // Wih1 kc=0 frags (streamed)
#pragma unroll
    for (int j = 0; j < 4; ++j)
      w1a[j] = *(const half8*)(w1base + (0 * 4 + j) * 512);

    float4_t acc0[4];
    if (do0) {                                    // layer 0, step tau
      half8 ax = cvt2f4(xrA, xrB);
#pragma unroll
      for (int j = 0; j < 4; ++j)
        acc0[j] = __builtin_amdgcn_mfma_f32_16x16x32_f16(ax, bwih0[j], zC, 0, 0, 0);
#pragma unroll
      for (int kc = 0; kc < 4; ++kc)
#pragma unroll
        for (int j = 0; j < 4; ++j)
          acc0[j] = __builtin_amdgcn_mfma_f32_16x16x32_f16(ah[kc], bwhh0[j][kc], acc0[j], 0, 0, 0);
      const int tn = (tau + 1 < T_) ? tau + 1 : T_ - 1;   // x prefetch (f32,
      xrA = *(const float4_t*)(xptr + tn * F_);           //  cvt at use so the
      xrB = *(const float4_t*)(xptr + tn * F_ + 4);       //  load spans iters)
    }
    if (do0) {                                    // layer-0 gates (acc0 dies)
#pragma unroll
      for (int rr = 0; rr < 2; ++rr) {
        const int ri = rsh + rr;
        const float gi = frcp(1.0f + fexp2(__builtin_fmaf(acc0[0][ri], -LOG2E, cI0)));
        const float gf = frcp(1.0f + fexp2(__builtin_fmaf(acc0[1][ri], -LOG2E, cF0)));
        const float gg = 1.0f - 2.0f * frcp(1.0f + fexp2(__builtin_fmaf(acc0[2][ri], 2.0f * LOG2E, cG0)));
        const float go = frcp(1.0f + fexp2(__builtin_fmaf(acc0[3][ri], -LOG2E, cO0)));
        float& cc = rr ? c01 : c00;
        cc = __builtin_fmaf(gf, cc, gi * gg);
        const float th = 1.0f - 2.0f * frcp(1.0f + fexp2(cc * (2.0f * LOG2E)));
        h0wr[(rowq + ri) * LSTR + colg] = (_Float16)(go * th);
      }
    }
    if (do1) {                                    // layer 1, step tau-1
      float4_t acc1[4];
      half8 w1b[4];                               // double-buffered kc stream:
#pragma unroll                                    //  load kc+1 while MFMAing kc
      for (int j = 0; j < 4; ++j)
        w1b[j] = *(const half8*)(w1base + (1 * 4 + j) * 512);
#pragma unroll
      for (int j = 0; j < 4; ++j)                 // ih kc=0 (w1a dies)
        acc1[j] = __builtin_amdgcn_mfma_f32_16x16x32_f16(ah[0], w1a[j], zC, 0, 0, 0);
#pragma unroll
      for (int j = 0; j < 4; ++j)
        w1a[j] = *(const half8*)(w1base + (2 * 4 + j) * 512);
#pragma unroll
      for (int j = 0; j < 4; ++j)                 // ih kc=1 (w1b dies)
        acc1[j] = __builtin_amdgcn_mfma_f32_16x16x32_f16(ah[1], w1b[j], acc1[j], 0, 0, 0);
#pragma unroll
      for (int j = 0; j < 4; ++j)
        w1b[j] = *(const half8*)(w1base + (3 * 4 + j) * 512);
#pragma unroll
      for (int j = 0; j < 4; ++j)                 // ih kc=2
        acc1[j] = __builtin_amdgcn_mfma_f32_16x16x32_f16(ah[2], w1a[j], acc1[j], 0, 0, 0);
      half8 a1h[4];                               // h1(tau-2)
#pragma unroll
      for (int kc = 0; kc < 4; ++kc)
        a1h[kc] = *(const half8*)(h1rd + aoff + kc * 32);
#pragma unroll
      for (int j = 0; j < 4; ++j)                 // ih kc=3
        acc1[j] = __builtin_amdgcn_mfma_f32_16x16x32_f16(ah[3], w1b[j], acc1[j], 0, 0, 0);
#pragma unroll
      for (int kc = 0; kc < 4; ++kc)              // hh (register-resident B)
#pragma unroll
        for (int j = 0; j < 4; ++j)
          acc1[j] = __builtin_amdgcn_mfma_f32_16x16x32_f16(a1h[kc], bwhh1[j][kc], acc1[j], 0, 0, 0);
#pragma unroll
      for (int rr = 0; rr < 2; ++rr) {            // layer-1 gates
        const int ri = rsh + rr;
        const float gi = frcp(1.0f + fexp2(__builtin_fmaf(acc1[0][ri], -LOG2E, cI1)));
        const float gf = frcp(1.0f + fexp2(__builtin_fmaf(acc1[1][ri], -LOG2E, cF1)));
        const float gg = 1.0f - 2.0f * frcp(1.0f + fexp2(__builtin_fmaf(acc1[2][ri], 2.0f * LOG2E, cG1)));
        const float go = frcp(1.0f + fexp2(__builtin_fmaf(acc1[3][ri], -LOG2E, cO1)));
        float& cc = rr ? c11 : c10;
        cc = __builtin_fmaf(gf, cc, gi * gg);
        const float th = 1.0f - 2.0f * frcp(1.0f + fexp2(cc * (2.0f * LOG2E)));
        h1wr[(rowq + ri) * LSTR + colg] = (_Float16)(go * th);
      }
    }
    BARRIER_LGKM();
  }

  // ---- FC head: out[row] = sum_c h1_last[row][c]*Wfc[c] + bfc ----
  // h1(T-1) sits in lds_h1 + H0SZ (tau=T_ wrote it there); read back the
  // two values this lane produced instead of carrying them in registers.
  const float wfcv = Wfc[colg];
  float p0 = (float)lds_h1[H0SZ + (rowq + rsh + 0) * LSTR + colg] * wfcv;
  float p1 = (float)lds_h1[H0SZ + (rowq + rsh + 1) * LSTR + colg] * wfcv;
#pragma unroll
  for (int m = 1; m < 16; m <<= 1) {
    p0 += __shfl_xor(p0, m);
    p1 += __shfl_xor(p1, m);
  }
  if (n == 0) {
    lds_fc[w][rowq + rsh + 0] = p0;
    lds_fc[w][rowq + rsh + 1] = p1;
  }
  __syncthreads();
  if (tid < 8) {
    float s = bfc[0];
#pragma unroll
    for (int wv = 0; wv < 8; ++wv) s += lds_fc[wv][tid];
    out[rbase + tid] = s;
  }
}

extern "C" void kernel_launch(void* const* d_in, const int* in_sizes, int n_in,
                              void* d_out, int out_size, void* d_ws, size_t ws_size,
                              hipStream_t stream) {
  const float* x    = (const float*)d_in[0];
  const float* Wih0 = (const float*)d_in[1];
  const float* Whh0 = (const float*)d_in[2];
  const float* b0   = (const float*)d_in[3];
  const float* Wih1 = (const float*)d_in[4];
  const float* Whh1 = (const float*)d_in[5];
  const float* b1   = (const float*)d_in[6];
  const float* Wfc  = (const float*)d_in[7];
  const float* bfc  = (const float*)d_in[8];
  float* outp = (float*)d_out;
  (void)d_ws; (void)ws_size;

  lstm_fused<<<B_ / 8, 512, 0, stream>>>(x, Wih0, Whh0, b0, Wih1, Whh1, b1,
                                         Wfc, bfc, outp);
}